// Round 1
// baseline (615.412 us; speedup 1.0000x reference)
//
#include <hip/hip_runtime.h>
#include <stdint.h>

// Problem constants
#define T_   4
#define B_   16
#define NT_  196
#define C_   384
#define H_   12
#define M_   12544              // T_*B_*NT_
#define PBUF_ELEMS 4816896      // M_*C_
#define NB_STATS 98             // stats blocks (128 rows each)
#define PACK_ELEMS 150528       // T_*B_*H_*NT_

// ---------------- reductions for scale factors ----------------
__global__ __launch_bounds__(256) void init_slots_kernel(unsigned* slots) {
  if (threadIdx.x < 16) slots[threadIdx.x] = 0u;
}

__global__ __launch_bounds__(256) void absmax_kernel(const float* __restrict__ x, int n,
                                                     unsigned* __restrict__ slot) {
  float m = 0.f;
  for (long i = (long)blockIdx.x * 256 + threadIdx.x; i < n; i += (long)gridDim.x * 256)
    m = fmaxf(m, fabsf(x[i]));
#pragma unroll
  for (int o = 32; o > 0; o >>= 1) m = fmaxf(m, __shfl_down(m, o));
  __shared__ float sm[4];
  int wid = threadIdx.x >> 6, lane = threadIdx.x & 63;
  if (lane == 0) sm[wid] = m;
  __syncthreads();
  if (threadIdx.x == 0) {
    m = fmaxf(fmaxf(sm[0], sm[1]), fmaxf(sm[2], sm[3]));
    atomicMax(slot, __float_as_uint(m));
  }
}

// SC[0]=SN2(x), SC[1..4]=SN1(q,k,v,p), SC[5]=SN2 for spike input (=32)
__global__ void scales_kernel(const unsigned* __restrict__ slots, float* __restrict__ SC) {
  if (threadIdx.x == 0 && blockIdx.x == 0) {
    for (int i = 0; i < 5; ++i) {
      float m = __uint_as_float(slots[i]);
      if (m == 0.f) m = 1.f;
      float q = floorf(32.f / m);          // floor(N_SC/m), f32 like jnp
      float sn = 0.f;                      // q==0 -> 2^-inf == 0
      if (q >= 1.f) { unsigned qi = (unsigned)q; sn = (float)(1u << (31 - __clz((int)qi))); }
      SC[i] = sn;
    }
    SC[5] = 32.f;  // spike input: max is 1 (or 0 -> guard 1); floor(32/1)=32 -> 2^5
  }
}

// ---------------- SC-quantized GEMM: out = (trunc((aa@bb^T)/SN2)+cc)/SN1 ----------------
// A: M x 384 row-major (raw values; aa = trunc(A*SN2) on the fly)
// W: 384 x 384 row-major (out,k); bb = trunc(W*SN1) on the fly
#define BM 64
#define BN 64
#define BK 32
__global__ __launch_bounds__(256) void sc_gemm_kernel(
    const float* __restrict__ A, const float* __restrict__ W,
    const float* __restrict__ bias, const float* __restrict__ SC,
    int sn2_slot, int sn1_slot, float* __restrict__ out) {
  __shared__ float As[BK][BM];
  __shared__ float Bs[BK][BN];
  const float SN2 = SC[sn2_slot];
  const float SN1 = SC[sn1_slot];
  const int tid = threadIdx.x;
  const int m0 = blockIdx.x * BM;
  const int n0 = blockIdx.y * BN;
  const int ty = tid >> 4, tx = tid & 15;
  float acc[4][4] = {};
  for (int k0 = 0; k0 < C_; k0 += BK) {
#pragma unroll
    for (int q = 0; q < 2; ++q) {
      int lidx = tid + q * 256;
      int row = lidx >> 3, c4 = lidx & 7;
      const float4 av = *reinterpret_cast<const float4*>(A + (size_t)(m0 + row) * C_ + k0 + c4 * 4);
      As[c4 * 4 + 0][row] = truncf(av.x * SN2);
      As[c4 * 4 + 1][row] = truncf(av.y * SN2);
      As[c4 * 4 + 2][row] = truncf(av.z * SN2);
      As[c4 * 4 + 3][row] = truncf(av.w * SN2);
      const float4 bv = *reinterpret_cast<const float4*>(W + (size_t)(n0 + row) * C_ + k0 + c4 * 4);
      Bs[c4 * 4 + 0][row] = truncf(bv.x * SN1);
      Bs[c4 * 4 + 1][row] = truncf(bv.y * SN1);
      Bs[c4 * 4 + 2][row] = truncf(bv.z * SN1);
      Bs[c4 * 4 + 3][row] = truncf(bv.w * SN1);
    }
    __syncthreads();
#pragma unroll
    for (int kk = 0; kk < BK; ++kk) {
      float4 a4 = *reinterpret_cast<const float4*>(&As[kk][ty * 4]);
      float4 b4 = *reinterpret_cast<const float4*>(&Bs[kk][tx * 4]);
      acc[0][0] += a4.x * b4.x; acc[0][1] += a4.x * b4.y; acc[0][2] += a4.x * b4.z; acc[0][3] += a4.x * b4.w;
      acc[1][0] += a4.y * b4.x; acc[1][1] += a4.y * b4.y; acc[1][2] += a4.y * b4.z; acc[1][3] += a4.y * b4.w;
      acc[2][0] += a4.z * b4.x; acc[2][1] += a4.z * b4.y; acc[2][2] += a4.z * b4.z; acc[2][3] += a4.z * b4.w;
      acc[3][0] += a4.w * b4.x; acc[3][1] += a4.w * b4.y; acc[3][2] += a4.w * b4.z; acc[3][3] += a4.w * b4.w;
    }
    __syncthreads();
  }
#pragma unroll
  for (int r = 0; r < 4; ++r) {
    int m = m0 + ty * 4 + r;
#pragma unroll
    for (int cq = 0; cq < 4; ++cq) {
      int n = n0 + tx * 4 + cq;
      float cc = truncf(bias[n] * SN1);
      out[(size_t)m * C_ + n] = (truncf(acc[r][cq] / SN2) + cc) / SN1;  // exact: SN2,SN1 pow2
    }
  }
}

// ---------------- BN statistics (f64, matches np/f64 closely) ----------------
// partial[blk][c][2] : sum, sumsq over 128 rows
__global__ __launch_bounds__(384) void stats_partial_kernel(const float* __restrict__ buf,
                                                            double* __restrict__ partial) {
  int c = threadIdx.x;
  int blk = blockIdx.x;
  const float* p = buf + (size_t)blk * 128 * C_ + c;
  double s = 0.0, s2 = 0.0;
  for (int r = 0; r < 128; ++r) {
    double v = (double)p[(size_t)r * C_];
    s += v; s2 += v * v;
  }
  partial[((size_t)blk * C_ + c) * 2 + 0] = s;
  partial[((size_t)blk * C_ + c) * 2 + 1] = s2;
}

// bn[c][2] = {mean_f32, sqrt(var+1e-5)_f32}; var uses the f32-rounded mean (matches jnp)
__global__ __launch_bounds__(384) void stats_final_kernel(const double* __restrict__ partial,
                                                          float* __restrict__ bn) {
  int c = threadIdx.x;
  double s = 0.0, s2 = 0.0;
  for (int b = 0; b < NB_STATS; ++b) {
    s  += partial[((size_t)b * C_ + c) * 2 + 0];
    s2 += partial[((size_t)b * C_ + c) * 2 + 1];
  }
  double mean = s / (double)M_;
  float m32 = (float)mean;
  double md = (double)m32;
  double var = (s2 - 2.0 * md * s + (double)M_ * md * md) / (double)M_;
  float v32 = (float)var;
  bn[c * 2 + 0] = m32;
  bn[c * 2 + 1] = sqrtf(v32 + 1e-5f);
}

// ---------------- LIF ----------------
__device__ __forceinline__ float lif_step(float& v, float x, float vth) {
  v = v + (x - v) * 0.5f;                 // /TAU, TAU=2.0 -> exact
  float u = v - vth;
  float spike = (u >= 0.0f) ? 1.0f : 0.0f;
  v = (u >= 0.0f) ? 0.0f : v;             // hard reset
  return spike;
}

// BN + LIF + bit-pack spikes into per-(t,b,h,n) u32 masks (d=32 bits)
__global__ __launch_bounds__(384) void bn_lif_pack_kernel(
    const float* __restrict__ pbuf, const float* __restrict__ bn,
    const float* __restrict__ g, const float* __restrict__ beta,
    uint32_t* __restrict__ pack) {
  int c = threadIdx.x;
  int n = blockIdx.x;   // 0..195
  int b = blockIdx.y;   // 0..15
  float mean = bn[c * 2 + 0], sd = bn[c * 2 + 1];
  float gg = g[c], bb = beta[c];
  int h = c >> 5;
  float v = 0.f;
  for (int t = 0; t < T_; ++t) {
    size_t row = (size_t)(t * B_ + b) * NT_ + n;
    float p = pbuf[row * C_ + c];
    float o = (gg * (p - mean)) / sd + bb;
    float spike = lif_step(v, o, 1.0f);
    unsigned long long m = __ballot(spike != 0.0f);
    if ((c & 31) == 0) {
      uint32_t part = (c & 32) ? (uint32_t)(m >> 32) : (uint32_t)m;
      pack[((size_t)(t * B_ + b) * H_ + h) * NT_ + n] = part;
    }
  }
}

// ---------------- attention: y = (q@k^T * 0.125) @ v via popcount on packed spikes ----------
__global__ __launch_bounds__(256) void attn_kernel(
    const uint32_t* __restrict__ qp, const uint32_t* __restrict__ kp,
    const uint32_t* __restrict__ vp, float* __restrict__ y) {
  __shared__ uint32_t ks[NT_], vs[NT_];
  int tbh = blockIdx.x;  // (t*B+b)*H + h
  int tid = threadIdx.x;
  if (tid < NT_) {
    ks[tid] = kp[(size_t)tbh * NT_ + tid];
    vs[tid] = vp[(size_t)tbh * NT_ + tid];
  }
  __syncthreads();
  if (tid >= NT_) return;
  uint32_t qm = qp[(size_t)tbh * NT_ + tid];
  int acc[32];
#pragma unroll
  for (int d = 0; d < 32; ++d) acc[d] = 0;
  for (int m = 0; m < NT_; ++m) {
    uint32_t km = ks[m], vm = vs[m];
    int s = __popc(qm & km);
#pragma unroll
    for (int d = 0; d < 32; ++d) acc[d] += (int)((vm >> d) & 1u) * s;
  }
  int t_b = tbh / H_, h = tbh % H_;
  float* yp = y + ((size_t)t_b * NT_ + tid) * C_ + h * 32;
#pragma unroll
  for (int d = 0; d < 32; ++d) yp[d] = 0.125f * (float)acc[d];  // exact: multiples of 1/8
}

// attn_lif (v_th=0.5), spikes written in place
__global__ __launch_bounds__(384) void lif_inplace_kernel(float* __restrict__ y, float vth) {
  int c = threadIdx.x, n = blockIdx.x, b = blockIdx.y;
  float v = 0.f;
  for (int t = 0; t < T_; ++t) {
    size_t idx = ((size_t)(t * B_ + b) * NT_ + n) * C_ + c;
    y[idx] = lif_step(v, y[idx], vth);
  }
}

// final BN + LIF -> d_out (f32 spikes)
__global__ __launch_bounds__(384) void bn_lif_out_kernel(
    const float* __restrict__ p2, const float* __restrict__ bn,
    const float* __restrict__ g, const float* __restrict__ beta,
    float* __restrict__ out) {
  int c = threadIdx.x, n = blockIdx.x, b = blockIdx.y;
  float mean = bn[c * 2 + 0], sd = bn[c * 2 + 1];
  float gg = g[c], bb = beta[c];
  float v = 0.f;
  for (int t = 0; t < T_; ++t) {
    size_t idx = ((size_t)(t * B_ + b) * NT_ + n) * C_ + c;
    float o = (gg * (p2[idx] - mean)) / sd + bb;
    out[idx] = lif_step(v, o, 1.0f);
  }
}

// ---------------- launcher ----------------
extern "C" void kernel_launch(void* const* d_in, const int* in_sizes, int n_in,
                              void* d_out, int out_size, void* d_ws, size_t ws_size,
                              hipStream_t stream) {
  (void)in_sizes; (void)n_in; (void)out_size; (void)ws_size;
  const float* x = (const float*)d_in[0];
  const float* W[4]  = {(const float*)d_in[1],  (const float*)d_in[5],
                        (const float*)d_in[9],  (const float*)d_in[13]};
  const float* bv[4] = {(const float*)d_in[2],  (const float*)d_in[6],
                        (const float*)d_in[10], (const float*)d_in[14]};
  const float* g[4]  = {(const float*)d_in[3],  (const float*)d_in[7],
                        (const float*)d_in[11], (const float*)d_in[15]};
  const float* be[4] = {(const float*)d_in[4],  (const float*)d_in[8],
                        (const float*)d_in[12], (const float*)d_in[16]};
  float* out = (float*)d_out;

  char* ws = (char*)d_ws;
  unsigned* slots  = (unsigned*)ws;                        // 16 u32
  float*    SC     = (float*)(ws + 64);                    // 8 f32
  float*    bnp    = (float*)(ws + 128);                   // [4][384][2] f32
  double*   part   = (double*)(ws + 16384);                // [4][98][384][2] f64 (~4.8MB)
  uint32_t* pack   = (uint32_t*)(ws + 5ull * 1024 * 1024); // [3][150528] u32 (~1.8MB)
  float*    pbuf   = (float*)(ws + 8ull * 1024 * 1024);    // [3][12544][384] f32 (~58MB)
  const size_t PPS = (size_t)NB_STATS * C_ * 2;            // partial elems per set

  init_slots_kernel<<<1, 64, 0, stream>>>(slots);
  absmax_kernel<<<1024, 256, 0, stream>>>(x, PBUF_ELEMS, slots + 0);
  for (int s = 0; s < 4; ++s) {
    absmax_kernel<<<64, 256, 0, stream>>>(W[s], C_ * C_, slots + 1 + s);
    absmax_kernel<<<1, 256, 0, stream>>>(bv[s], C_, slots + 1 + s);
  }
  scales_kernel<<<1, 1, 0, stream>>>(slots, SC);

  // stage 1: q,k,v SC-linear
  for (int s = 0; s < 3; ++s)
    sc_gemm_kernel<<<dim3(M_ / BM, C_ / BN), 256, 0, stream>>>(
        x, W[s], bv[s], SC, 0, 1 + s, pbuf + (size_t)s * PBUF_ELEMS);
  for (int s = 0; s < 3; ++s)
    stats_partial_kernel<<<NB_STATS, 384, 0, stream>>>(pbuf + (size_t)s * PBUF_ELEMS, part + s * PPS);
  for (int s = 0; s < 3; ++s)
    stats_final_kernel<<<1, 384, 0, stream>>>(part + s * PPS, bnp + s * C_ * 2);
  for (int s = 0; s < 3; ++s)
    bn_lif_pack_kernel<<<dim3(NT_, B_), 384, 0, stream>>>(
        pbuf + (size_t)s * PBUF_ELEMS, bnp + s * C_ * 2, g[s], be[s], pack + (size_t)s * PACK_ELEMS);

  // attention (reuses pbuf[0] as y) + attn_lif (v_th=0.5, in place)
  attn_kernel<<<T_ * B_ * H_, 256, 0, stream>>>(pack, pack + PACK_ELEMS, pack + 2 * PACK_ELEMS, pbuf);
  lif_inplace_kernel<<<dim3(NT_, B_), 384, 0, stream>>>(pbuf, 0.5f);

  // stage 2: proj SC-linear (spike input -> SN2=32, slot 5); p2 in pbuf[1]
  sc_gemm_kernel<<<dim3(M_ / BM, C_ / BN), 256, 0, stream>>>(
      pbuf, W[3], bv[3], SC, 5, 4, pbuf + PBUF_ELEMS);
  stats_partial_kernel<<<NB_STATS, 384, 0, stream>>>(pbuf + PBUF_ELEMS, part + 3 * PPS);
  stats_final_kernel<<<1, 384, 0, stream>>>(part + 3 * PPS, bnp + 3 * C_ * 2);
  bn_lif_out_kernel<<<dim3(NT_, B_), 384, 0, stream>>>(pbuf + PBUF_ELEMS, bnp + 3 * C_ * 2, g[3], be[3], out);
}

// Round 2
// 307.883 us; speedup vs baseline: 1.9989x; 1.9989x over previous
//
#include <hip/hip_runtime.h>
#include <hip/hip_bf16.h>
#include <stdint.h>

#define T_   4
#define B_   16
#define NT_  196
#define C_   384
#define H_   12
#define M_   12544
#define PBUF_ELEMS 4816896

typedef __attribute__((ext_vector_type(8))) short bf16x8;
typedef __attribute__((ext_vector_type(4))) float f32x4;

__device__ __forceinline__ void gload_lds16(const void* g, void* l) {
  typedef __attribute__((address_space(1))) const unsigned int GU32;
  typedef __attribute__((address_space(3))) unsigned int LU32;
  __builtin_amdgcn_global_load_lds((GU32*)g, (LU32*)l, 16, 0, 0);
}

__device__ __forceinline__ short f2bf_bits(float f) {
  __hip_bfloat16 h = __float2bfloat16(f);
  return *(short*)&h;
}

// ---------------- scale factors ----------------
__global__ __launch_bounds__(64) void init_slots_kernel(unsigned* slots) {
  if (threadIdx.x < 16) slots[threadIdx.x] = 0u;
}

__global__ __launch_bounds__(256) void absmax_kernel(const float* __restrict__ x, int n,
                                                     unsigned* __restrict__ slot) {
  float m = 0.f;
  for (long i = (long)blockIdx.x * 256 + threadIdx.x; i < n; i += (long)gridDim.x * 256)
    m = fmaxf(m, fabsf(x[i]));
#pragma unroll
  for (int o = 32; o > 0; o >>= 1) m = fmaxf(m, __shfl_down(m, o));
  __shared__ float sm[4];
  int wid = threadIdx.x >> 6, lane = threadIdx.x & 63;
  if (lane == 0) sm[wid] = m;
  __syncthreads();
  if (threadIdx.x == 0) {
    m = fmaxf(fmaxf(sm[0], sm[1]), fmaxf(sm[2], sm[3]));
    atomicMax(slot, __float_as_uint(m));
  }
}

// SC[0]=SN2(x), SC[1..4]=SN1(q,k,v,p), SC[5]=SN2 for spike input (=32)
__global__ void scales_kernel(const unsigned* __restrict__ slots, float* __restrict__ SC) {
  if (threadIdx.x == 0 && blockIdx.x == 0) {
    for (int i = 0; i < 5; ++i) {
      float m = __uint_as_float(slots[i]);
      if (m == 0.f) m = 1.f;
      float q = floorf(32.f / m);
      float sn = 0.f;
      if (q >= 1.f) { unsigned qi = (unsigned)q; sn = (float)(1u << (31 - __clz((int)qi))); }
      SC[i] = sn;
    }
    SC[5] = 32.f;
  }
}

// ---------------- quantize to bf16 (exact: values are small integers) ----------------
__global__ __launch_bounds__(256) void quant_x_kernel(const float* __restrict__ x,
                                                      const float* __restrict__ SC,
                                                      short* __restrict__ xq) {
  const float sn2 = SC[0];
  size_t i = ((size_t)blockIdx.x * 256 + threadIdx.x) * 4;
  float4 v = *reinterpret_cast<const float4*>(x + i);
  short4 o;
  o.x = f2bf_bits(truncf(v.x * sn2));
  o.y = f2bf_bits(truncf(v.y * sn2));
  o.z = f2bf_bits(truncf(v.z * sn2));
  o.w = f2bf_bits(truncf(v.w * sn2));
  *reinterpret_cast<short4*>(xq + i) = o;
}

__global__ __launch_bounds__(256) void quant_w_kernel(const float* __restrict__ W,
                                                      const float* __restrict__ bias,
                                                      const float* __restrict__ SC, int sn1_slot,
                                                      short* __restrict__ wq, float* __restrict__ ccq) {
  const float sn1 = SC[sn1_slot];
  int gid = blockIdx.x * 256 + threadIdx.x;
  wq[gid] = f2bf_bits(truncf(W[gid] * sn1));
  if (gid < C_) ccq[gid] = truncf(bias[gid] * sn1);
}

// ---------------- MFMA SC-GEMM: p = (trunc((aa@bb^T)/SN2)+cc)/SN1, + exact i64 stats ----------------
// Aq: M x 384 bf16 (pre-quantized ints), Bq: 384 x 384 bf16 (N x K), 128x128 tile, BK=64.
// LDS XOR-swizzle (slot ^= row&7) applied on the GLOBAL source (rule #21) and on ds_read.
__global__ __launch_bounds__(256) void mfma_gemm_kernel(
    const short* __restrict__ Aq, const short* __restrict__ Bq,
    const float* __restrict__ cc, const float* __restrict__ SC,
    int sn2_slot, int sn1_slot,
    float* __restrict__ out, long long* __restrict__ part) {
  __shared__ short As[8192];   // 128 rows x 64 bf16 (128B/row), swizzled
  __shared__ short Bs[8192];
  __shared__ unsigned long long sred[128][2];
  const int tid = threadIdx.x;
  const int lane = tid & 63;
  const int wid = tid >> 6;
  const int wm = wid >> 1, wn = wid & 1;
  const int m0 = blockIdx.x * 128;
  const int n0 = blockIdx.y * 128;
  if (tid < 128) { sred[tid][0] = 0ull; sred[tid][1] = 0ull; }
  f32x4 acc[4][4];
#pragma unroll
  for (int i = 0; i < 4; ++i)
#pragma unroll
    for (int j = 0; j < 4; ++j) acc[i][j] = (f32x4){0.f, 0.f, 0.f, 0.f};

  for (int k0 = 0; k0 < C_; k0 += 64) {
#pragma unroll
    for (int p = 0; p < 4; ++p) {
      int o = p * 4096 + tid * 16;       // linear dest byte offset in tile
      int row = o >> 7;                  // 128 B per row
      int slot = (o >> 4) & 7;
      int hs = slot ^ (row & 7);         // inverse-swizzled global slot
      int ldsoff = p * 4096 + (tid & ~63) * 16;  // wave-uniform base
      gload_lds16(Aq + (size_t)(m0 + row) * C_ + k0 + hs * 8, (char*)As + ldsoff);
      gload_lds16(Bq + (size_t)(n0 + row) * C_ + k0 + hs * 8, (char*)Bs + ldsoff);
    }
    __syncthreads();
#pragma unroll
    for (int kk = 0; kk < 2; ++kk) {
      bf16x8 af[4], bfr[4];
#pragma unroll
      for (int i = 0; i < 4; ++i) {
        int r = wm * 64 + i * 16 + (lane & 15);
        int h = kk * 4 + (lane >> 4);
        af[i] = *(const bf16x8*)((const char*)As + r * 128 + ((h ^ (r & 7)) << 4));
        int c = wn * 64 + i * 16 + (lane & 15);
        bfr[i] = *(const bf16x8*)((const char*)Bs + c * 128 + ((h ^ (c & 7)) << 4));
      }
#pragma unroll
      for (int i = 0; i < 4; ++i)
#pragma unroll
        for (int j = 0; j < 4; ++j)
          acc[i][j] = __builtin_amdgcn_mfma_f32_16x16x32_bf16(af[i], bfr[j], acc[i][j], 0, 0, 0);
    }
    __syncthreads();
  }
  const float SN2 = SC[sn2_slot], SN1 = SC[sn1_slot];
  const float invSN2 = 1.0f / SN2, invSN1 = 1.0f / SN1;  // exact pow2
  long long s1[4] = {0, 0, 0, 0}, s2[4] = {0, 0, 0, 0};
#pragma unroll
  for (int j = 0; j < 4; ++j) {
    int gcol = n0 + wn * 64 + j * 16 + (lane & 15);
    float ccv = cc[gcol];
#pragma unroll
    for (int i = 0; i < 4; ++i) {
#pragma unroll
      for (int r = 0; r < 4; ++r) {
        int grow = m0 + wm * 64 + i * 16 + (lane >> 4) * 4 + r;  // verified C/D map (m89)
        float qf = truncf(acc[i][j][r] * invSN2) + ccv;          // exact integer
        out[(size_t)grow * C_ + gcol] = qf * invSN1;
        long long qi = (long long)qf;
        s1[j] += qi; s2[j] += qi * qi;
      }
    }
  }
#pragma unroll
  for (int j = 0; j < 4; ++j) {
    s1[j] += __shfl_xor(s1[j], 16); s1[j] += __shfl_xor(s1[j], 32);
    s2[j] += __shfl_xor(s2[j], 16); s2[j] += __shfl_xor(s2[j], 32);
  }
  if (lane < 16) {
#pragma unroll
    for (int j = 0; j < 4; ++j) {
      int cl = wn * 64 + j * 16 + lane;
      atomicAdd(&sred[cl][0], (unsigned long long)s1[j]);
      atomicAdd(&sred[cl][1], (unsigned long long)s2[j]);
    }
  }
  __syncthreads();
  if (tid < 128) {
    part[((size_t)blockIdx.x * C_ + n0 + tid) * 2 + 0] = (long long)sred[tid][0];
    part[((size_t)blockIdx.x * C_ + n0 + tid) * 2 + 1] = (long long)sred[tid][1];
  }
}

// ---------------- BN params from exact integer sums (bit-identical to round-1 f64 path) ----------------
__global__ __launch_bounds__(384) void stats_final_kernel(
    const long long* __restrict__ part, const float* __restrict__ SC, int sn1_slot,
    float* __restrict__ bn) {
  int c = threadIdx.x;
  long long S1 = 0, S2 = 0;
  for (int b = 0; b < 98; ++b) {
    S1 += part[((size_t)b * C_ + c) * 2 + 0];
    S2 += part[((size_t)b * C_ + c) * 2 + 1];
  }
  double inv = 1.0 / (double)SC[sn1_slot];
  double s = (double)S1 * inv;          // exact
  double s2 = (double)S2 * inv * inv;   // exact
  double mean = s / (double)M_;
  float m32 = (float)mean;
  double md = (double)m32;
  double var = (s2 - 2.0 * md * s + (double)M_ * md * md) / (double)M_;
  float v32 = (float)var;
  bn[c * 2 + 0] = m32;
  bn[c * 2 + 1] = sqrtf(v32 + 1e-5f);
}

// ---------------- LIF ----------------
__device__ __forceinline__ float lif_step(float& v, float x, float vth) {
  v = v + (x - v) * 0.5f;
  float u = v - vth;
  float spike = (u >= 0.0f) ? 1.0f : 0.0f;
  v = (u >= 0.0f) ? 0.0f : v;
  return spike;
}

// BN + LIF + bit-pack spikes into per-(t,b,h,n) u32 masks (d=32 bits)
__global__ __launch_bounds__(384) void bn_lif_pack_kernel(
    const float* __restrict__ pbuf, const float* __restrict__ bn,
    const float* __restrict__ g, const float* __restrict__ beta,
    uint32_t* __restrict__ pack) {
  int c = threadIdx.x;
  int n = blockIdx.x;
  int b = blockIdx.y;
  float mean = bn[c * 2 + 0], sd = bn[c * 2 + 1];
  float gg = g[c], bb = beta[c];
  int h = c >> 5;
  float v = 0.f;
  for (int t = 0; t < T_; ++t) {
    size_t row = (size_t)(t * B_ + b) * NT_ + n;
    float p = pbuf[row * C_ + c];
    float o = (gg * (p - mean)) / sd + bb;
    float spike = lif_step(v, o, 1.0f);
    unsigned long long m = __ballot(spike != 0.0f);
    if ((c & 31) == 0) {
      uint32_t part_ = (c & 32) ? (uint32_t)(m >> 32) : (uint32_t)m;
      pack[((size_t)(t * B_ + b) * H_ + h) * NT_ + n] = part_;
    }
  }
}

// ---------------- attention via Z = k^T v (32x32 int), fused attn_lif, writes 32*spike bf16 ----------
__global__ __launch_bounds__(256) void attn_fused_kernel(
    const uint32_t* __restrict__ qp, const uint32_t* __restrict__ kp,
    const uint32_t* __restrict__ vp, short* __restrict__ yq) {
  __shared__ uint32_t qs[256], ksm[256], vsm[256];
  __shared__ uint32_t kT[32][8], vT[32][8];
  __shared__ int Z[32][32];
  const int bh = blockIdx.x;
  const int b = bh / H_, h = bh % H_;
  const int tid = threadIdx.x, lane = tid & 63, w = tid >> 6;
  const int d = tid & 31, nn = tid >> 5;
  float vst[25];
#pragma unroll
  for (int i = 0; i < 25; ++i) vst[i] = 0.f;
  const short one32 = f2bf_bits(32.f);
  const short zer = f2bf_bits(0.f);
  for (int t = 0; t < T_; ++t) {
    size_t base = ((size_t)(t * B_ + b) * H_ + h) * NT_;
    qs[tid]  = (tid < NT_) ? qp[base + tid] : 0u;
    ksm[tid] = (tid < NT_) ? kp[base + tid] : 0u;
    vsm[tid] = (tid < NT_) ? vp[base + tid] : 0u;
    __syncthreads();
    // bit-transpose k,v along m (wave w covers m in [64w, 64w+64))
    uint32_t km = ksm[w * 64 + lane], vm = vsm[w * 64 + lane];
#pragma unroll
    for (int j = 0; j < 32; ++j) {
      unsigned long long bk = __ballot((km >> j) & 1u);
      unsigned long long bv = __ballot((vm >> j) & 1u);
      if (lane == 0) {
        kT[j][2 * w] = (uint32_t)bk; kT[j][2 * w + 1] = (uint32_t)(bk >> 32);
        vT[j][2 * w] = (uint32_t)bv; vT[j][2 * w + 1] = (uint32_t)(bv >> 32);
      }
    }
    __syncthreads();
    // Z[j][d] = sum_m k[m][j]*v[m][d] (exact int <= 196)
    for (int pz = tid; pz < 1024; pz += 256) {
      int j = pz >> 5, dd = pz & 31;
      int z = 0;
#pragma unroll
      for (int ww = 0; ww < 8; ++ww) z += __popc(kT[j][ww] & vT[dd][ww]);
      Z[j][dd] = z;
    }
    __syncthreads();
    int zc[32];
#pragma unroll
    for (int j = 0; j < 32; ++j) zc[j] = Z[j][d];   // column d in registers
#pragma unroll
    for (int i = 0; i < 25; ++i) {
      int n = i * 8 + nn;
      if (n < NT_) {
        uint32_t qm = qs[n];
        int a = 0;
#pragma unroll
        for (int j = 0; j < 32; ++j) a += ((qm >> j) & 1u) ? zc[j] : 0;
        float y = 0.125f * (float)a;     // exact multiple of 1/8
        float v = vst[i];
        v = v + (y - v) * 0.5f;
        short outv;
        if (v - 0.5f >= 0.f) { v = 0.f; outv = one32; } else { outv = zer; }
        vst[i] = v;
        yq[((size_t)(t * B_ + b) * NT_ + n) * C_ + h * 32 + d] = outv;
      }
    }
    __syncthreads();
  }
}

// final BN + LIF -> d_out (f32 spikes)
__global__ __launch_bounds__(384) void bn_lif_out_kernel(
    const float* __restrict__ p2, const float* __restrict__ bn,
    const float* __restrict__ g, const float* __restrict__ beta,
    float* __restrict__ out) {
  int c = threadIdx.x, n = blockIdx.x, b = blockIdx.y;
  float mean = bn[c * 2 + 0], sd = bn[c * 2 + 1];
  float gg = g[c], bb = beta[c];
  float v = 0.f;
  for (int t = 0; t < T_; ++t) {
    size_t idx = ((size_t)(t * B_ + b) * NT_ + n) * C_ + c;
    float o = (gg * (p2[idx] - mean)) / sd + bb;
    out[idx] = lif_step(v, o, 1.0f);
  }
}

// ---------------- launcher ----------------
extern "C" void kernel_launch(void* const* d_in, const int* in_sizes, int n_in,
                              void* d_out, int out_size, void* d_ws, size_t ws_size,
                              hipStream_t stream) {
  (void)in_sizes; (void)n_in; (void)out_size; (void)ws_size;
  const float* x = (const float*)d_in[0];
  const float* W[4]  = {(const float*)d_in[1],  (const float*)d_in[5],
                        (const float*)d_in[9],  (const float*)d_in[13]};
  const float* bv[4] = {(const float*)d_in[2],  (const float*)d_in[6],
                        (const float*)d_in[10], (const float*)d_in[14]};
  const float* g[4]  = {(const float*)d_in[3],  (const float*)d_in[7],
                        (const float*)d_in[11], (const float*)d_in[15]};
  const float* be[4] = {(const float*)d_in[4],  (const float*)d_in[8],
                        (const float*)d_in[12], (const float*)d_in[16]};
  float* out = (float*)d_out;

  char* ws = (char*)d_ws;
  unsigned*  slots = (unsigned*)(ws + 0);
  float*     SC    = (float*)(ws + 64);
  float*     bnp   = (float*)(ws + 128);            // [4][384][2] f32
  float*     ccq   = (float*)(ws + 16384);          // [4][384] f32
  long long* part  = (long long*)(ws + 32768);      // [4][98][384][2] i64
  uint32_t*  pack  = (uint32_t*)(ws + 0x260000);    // [3][150528] u32
  short*     wq    = (short*)(ws + 0x420000);       // [4][384][384] bf16
  short*     xq    = (short*)(ws + 0x550000);       // [12544][384] bf16
  short*     yq    = (short*)(ws + 0xE80000);       // [12544][384] bf16
  float*     pbuf  = (float*)(ws + 0x17B0000);      // [12544][384] f32 (reused)
  const size_t PPS = (size_t)98 * C_ * 2;

  init_slots_kernel<<<1, 64, 0, stream>>>(slots);
  absmax_kernel<<<1024, 256, 0, stream>>>(x, PBUF_ELEMS, slots + 0);
  for (int s = 0; s < 4; ++s) {
    absmax_kernel<<<64, 256, 0, stream>>>(W[s], C_ * C_, slots + 1 + s);
    absmax_kernel<<<1, 256, 0, stream>>>(bv[s], C_, slots + 1 + s);
  }
  scales_kernel<<<1, 1, 0, stream>>>(slots, SC);

  quant_x_kernel<<<4704, 256, 0, stream>>>(x, SC, xq);
  for (int s = 0; s < 4; ++s)
    quant_w_kernel<<<576, 256, 0, stream>>>(W[s], bv[s], SC, 1 + s,
                                            wq + (size_t)s * 147456, ccq + s * C_);

  // stage 1: q,k,v — GEMM -> stats -> BN+LIF+pack (pbuf reused per s)
  for (int s = 0; s < 3; ++s) {
    mfma_gemm_kernel<<<dim3(98, 3), 256, 0, stream>>>(
        xq, wq + (size_t)s * 147456, ccq + s * C_, SC, 0, 1 + s, pbuf, part + s * PPS);
    stats_final_kernel<<<1, 384, 0, stream>>>(part + s * PPS, SC, 1 + s, bnp + s * C_ * 2);
    bn_lif_pack_kernel<<<dim3(NT_, B_), 384, 0, stream>>>(
        pbuf, bnp + s * C_ * 2, g[s], be[s], pack + (size_t)s * 150528);
  }

  // attention + attn_lif fused, writes 32*spike bf16 (stage-2 quantization folded, SN2=32)
  attn_fused_kernel<<<B_ * H_, 256, 0, stream>>>(pack, pack + 150528, pack + 2 * 150528, yq);

  // stage 2: proj GEMM -> stats -> BN+LIF -> out
  mfma_gemm_kernel<<<dim3(98, 3), 256, 0, stream>>>(
      yq, wq + 3ull * 147456, ccq + 3 * C_, SC, 5, 4, pbuf, part + 3 * PPS);
  stats_final_kernel<<<1, 384, 0, stream>>>(part + 3 * PPS, SC, 4, bnp + 3 * C_ * 2);
  bn_lif_out_kernel<<<dim3(NT_, B_), 384, 0, stream>>>(pbuf, bnp + 3 * C_ * 2, g[3], be[3], out);
}

// Round 3
// 252.269 us; speedup vs baseline: 2.4395x; 1.2205x over previous
//
#include <hip/hip_runtime.h>
#include <hip/hip_bf16.h>
#include <stdint.h>

#define T_   4
#define B_   16
#define NT_  196
#define C_   384
#define H_   12
#define M_   12544
#define NW_  1152              // 3*C_, wide stage-1 output
#define PBUF_ELEMS 4816896

typedef __attribute__((ext_vector_type(8))) short bf16x8;
typedef __attribute__((ext_vector_type(4))) float f32x4;

__device__ __forceinline__ void gload_lds16(const void* g, void* l) {
  typedef __attribute__((address_space(1))) const unsigned int GU32;
  typedef __attribute__((address_space(3))) unsigned int LU32;
  __builtin_amdgcn_global_load_lds((GU32*)g, (LU32*)l, 16, 0, 0);
}

__device__ __forceinline__ short f2bf_bits(float f) {
  __hip_bfloat16 h = __float2bfloat16(f);
  return *(short*)&h;
}

// ---------------- scale factors ----------------
__global__ __launch_bounds__(256) void absmax_x_kernel(const float* __restrict__ x, int n4,
                                                       unsigned* __restrict__ slot) {
  float m = 0.f;
  for (long i = (long)blockIdx.x * 256 + threadIdx.x; i < n4; i += (long)gridDim.x * 256) {
    float4 v = reinterpret_cast<const float4*>(x)[i];
    m = fmaxf(fmaxf(fmaxf(fabsf(v.x), fabsf(v.y)), fmaxf(fabsf(v.z), fabsf(v.w))), m);
  }
#pragma unroll
  for (int o = 32; o > 0; o >>= 1) m = fmaxf(m, __shfl_down(m, o));
  __shared__ float sm[4];
  int wid = threadIdx.x >> 6, lane = threadIdx.x & 63;
  if (lane == 0) sm[wid] = m;
  __syncthreads();
  if (threadIdx.x == 0) {
    m = fmaxf(fmaxf(sm[0], sm[1]), fmaxf(sm[2], sm[3]));
    atomicMax(slot, __float_as_uint(m));
  }
}

// all 4 weight matrices + biases in one dispatch; grid (64, 4)
__global__ __launch_bounds__(256) void absmax_wb_kernel(
    const float* __restrict__ W0, const float* __restrict__ W1,
    const float* __restrict__ W2, const float* __restrict__ W3,
    const float* __restrict__ b0, const float* __restrict__ b1,
    const float* __restrict__ b2, const float* __restrict__ b3,
    unsigned* __restrict__ slots) {
  int s = blockIdx.y;
  const float* W = (s == 0) ? W0 : (s == 1) ? W1 : (s == 2) ? W2 : W3;
  const float* bb = (s == 0) ? b0 : (s == 1) ? b1 : (s == 2) ? b2 : b3;
  float m = 0.f;
  for (int i = blockIdx.x * 256 + threadIdx.x; i < C_ * C_; i += 64 * 256)
    m = fmaxf(m, fabsf(W[i]));
  if (blockIdx.x == 0)
    for (int i = threadIdx.x; i < C_; i += 256) m = fmaxf(m, fabsf(bb[i]));
#pragma unroll
  for (int o = 32; o > 0; o >>= 1) m = fmaxf(m, __shfl_down(m, o));
  __shared__ float sm[4];
  int wid = threadIdx.x >> 6, lane = threadIdx.x & 63;
  if (lane == 0) sm[wid] = m;
  __syncthreads();
  if (threadIdx.x == 0) {
    m = fmaxf(fmaxf(sm[0], sm[1]), fmaxf(sm[2], sm[3]));
    atomicMax(slots + 1 + s, __float_as_uint(m));
  }
}

// SC[0]=SN2(x), SC[1..4]=SN1(q,k,v,p), SC[5]=SN2 spike input (=32)
__global__ __launch_bounds__(64) void scales_kernel(const unsigned* __restrict__ slots,
                                                    float* __restrict__ SC) {
  if (threadIdx.x == 0) {
    for (int i = 0; i < 5; ++i) {
      float m = __uint_as_float(slots[i]);
      if (m == 0.f) m = 1.f;
      float q = floorf(32.f / m);
      float sn = 0.f;
      if (q >= 1.f) { unsigned qi = (unsigned)q; sn = (float)(1u << (31 - __clz((int)qi))); }
      SC[i] = sn;
    }
    SC[5] = 32.f;
  }
}

// ---------------- quantize to bf16 (exact: small integers) ----------------
__global__ __launch_bounds__(256) void quant_x_kernel(const float* __restrict__ x,
                                                      const float* __restrict__ SC,
                                                      short* __restrict__ xq) {
  const float sn2 = SC[0];
  size_t i = ((size_t)blockIdx.x * 256 + threadIdx.x) * 4;
  float4 v = *reinterpret_cast<const float4*>(x + i);
  short4 o;
  o.x = f2bf_bits(truncf(v.x * sn2));
  o.y = f2bf_bits(truncf(v.y * sn2));
  o.z = f2bf_bits(truncf(v.z * sn2));
  o.w = f2bf_bits(truncf(v.w * sn2));
  *reinterpret_cast<short4*>(xq + i) = o;
}

// grid (576, 4): all four W/b
__global__ __launch_bounds__(256) void quant_w_kernel(
    const float* __restrict__ W0, const float* __restrict__ W1,
    const float* __restrict__ W2, const float* __restrict__ W3,
    const float* __restrict__ b0, const float* __restrict__ b1,
    const float* __restrict__ b2, const float* __restrict__ b3,
    const float* __restrict__ SC, short* __restrict__ wq, float* __restrict__ ccq) {
  int s = blockIdx.y;
  const float* W = (s == 0) ? W0 : (s == 1) ? W1 : (s == 2) ? W2 : W3;
  const float* bb = (s == 0) ? b0 : (s == 1) ? b1 : (s == 2) ? b2 : b3;
  const float sn1 = SC[1 + s];
  int gid = blockIdx.x * 256 + threadIdx.x;
  wq[(size_t)s * C_ * C_ + gid] = f2bf_bits(truncf(W[gid] * sn1));
  if (gid < C_) ccq[s * C_ + gid] = truncf(bb[gid] * sn1);
}

// ---------------- MFMA SC-GEMM + exact i64 stats ----------------
// Aq: M x 384 bf16, Bq: ldc x 384 bf16 (N x K). 128x128 tile, BK=64.
// SN1 slot = sn1_base + blockIdx.y/3 (stage1: 1+seg over N=1152; stage2: 4).
__global__ __launch_bounds__(256) void mfma_gemm_kernel(
    const short* __restrict__ Aq, const short* __restrict__ Bq,
    const float* __restrict__ cc, const float* __restrict__ SC,
    int sn2_slot, int sn1_base, int ldc,
    float* __restrict__ out, long long* __restrict__ part) {
  __shared__ short As[8192];   // 128 rows x 64 bf16, XOR-swizzled
  __shared__ short Bs[8192];
  __shared__ unsigned long long sred[128][2];
  const int tid = threadIdx.x;
  const int lane = tid & 63;
  const int wid = tid >> 6;
  const int wm = wid >> 1, wn = wid & 1;
  const int m0 = blockIdx.x * 128;
  const int n0 = blockIdx.y * 128;
  if (tid < 128) { sred[tid][0] = 0ull; sred[tid][1] = 0ull; }
  f32x4 acc[4][4];
#pragma unroll
  for (int i = 0; i < 4; ++i)
#pragma unroll
    for (int j = 0; j < 4; ++j) acc[i][j] = (f32x4){0.f, 0.f, 0.f, 0.f};

  for (int k0 = 0; k0 < C_; k0 += 64) {
#pragma unroll
    for (int p = 0; p < 4; ++p) {
      int o = p * 4096 + tid * 16;
      int row = o >> 7;
      int slot = (o >> 4) & 7;
      int hs = slot ^ (row & 7);                 // inverse-swizzled global slot
      int ldsoff = p * 4096 + (tid & ~63) * 16;  // wave-uniform base
      gload_lds16(Aq + (size_t)(m0 + row) * C_ + k0 + hs * 8, (char*)As + ldsoff);
      gload_lds16(Bq + (size_t)(n0 + row) * C_ + k0 + hs * 8, (char*)Bs + ldsoff);
    }
    __syncthreads();
#pragma unroll
    for (int kk = 0; kk < 2; ++kk) {
      bf16x8 af[4], bfr[4];
#pragma unroll
      for (int i = 0; i < 4; ++i) {
        int r = wm * 64 + i * 16 + (lane & 15);
        int h = kk * 4 + (lane >> 4);
        af[i] = *(const bf16x8*)((const char*)As + r * 128 + ((h ^ (r & 7)) << 4));
        int c = wn * 64 + i * 16 + (lane & 15);
        bfr[i] = *(const bf16x8*)((const char*)Bs + c * 128 + ((h ^ (c & 7)) << 4));
      }
#pragma unroll
      for (int i = 0; i < 4; ++i)
#pragma unroll
        for (int j = 0; j < 4; ++j)
          acc[i][j] = __builtin_amdgcn_mfma_f32_16x16x32_bf16(af[i], bfr[j], acc[i][j], 0, 0, 0);
    }
    __syncthreads();
  }
  const float SN2 = SC[sn2_slot], SN1 = SC[sn1_base + blockIdx.y / 3];
  const float invSN2 = 1.0f / SN2, invSN1 = 1.0f / SN1;  // exact pow2
  long long s1[4] = {0, 0, 0, 0}, s2[4] = {0, 0, 0, 0};
#pragma unroll
  for (int j = 0; j < 4; ++j) {
    int gcol = n0 + wn * 64 + j * 16 + (lane & 15);
    float ccv = cc[gcol];
#pragma unroll
    for (int i = 0; i < 4; ++i) {
#pragma unroll
      for (int r = 0; r < 4; ++r) {
        int grow = m0 + wm * 64 + i * 16 + (lane >> 4) * 4 + r;
        float qf = truncf(acc[i][j][r] * invSN2) + ccv;   // exact integer
        out[(size_t)grow * ldc + gcol] = qf * invSN1;
        long long qi = (long long)qf;
        s1[j] += qi; s2[j] += qi * qi;
      }
    }
  }
#pragma unroll
  for (int j = 0; j < 4; ++j) {
    s1[j] += __shfl_xor(s1[j], 16); s1[j] += __shfl_xor(s1[j], 32);
    s2[j] += __shfl_xor(s2[j], 16); s2[j] += __shfl_xor(s2[j], 32);
  }
  if (lane < 16) {
#pragma unroll
    for (int j = 0; j < 4; ++j) {
      int cl = wn * 64 + j * 16 + lane;
      atomicAdd(&sred[cl][0], (unsigned long long)s1[j]);
      atomicAdd(&sred[cl][1], (unsigned long long)s2[j]);
    }
  }
  __syncthreads();
  if (tid < 128) {
    part[((size_t)blockIdx.x * ldc + n0 + tid) * 2 + 0] = (long long)sred[tid][0];
    part[((size_t)blockIdx.x * ldc + n0 + tid) * 2 + 1] = (long long)sred[tid][1];
  }
}

// ---------------- BN params from exact integer sums; grid (nseg), 384 thr ----------------
__global__ __launch_bounds__(384) void stats_final_kernel(
    const long long* __restrict__ part, const float* __restrict__ SC, int sn1_base, int Ld,
    float* __restrict__ bn) {
  int c = blockIdx.x * 384 + threadIdx.x;
  long long S1 = 0, S2 = 0;
  for (int b = 0; b < 98; ++b) {
    S1 += part[((size_t)b * Ld + c) * 2 + 0];
    S2 += part[((size_t)b * Ld + c) * 2 + 1];
  }
  double inv = 1.0 / (double)SC[sn1_base + blockIdx.x];
  double s = (double)S1 * inv;
  double s2 = (double)S2 * inv * inv;
  double mean = s / (double)M_;
  float m32 = (float)mean;
  double md = (double)m32;
  double var = (s2 - 2.0 * md * s + (double)M_ * md * md) / (double)M_;
  bn[c * 2 + 0] = m32;
  bn[c * 2 + 1] = sqrtf((float)var + 1e-5f);
}

// ---------------- LIF ----------------
__device__ __forceinline__ float lif_step(float& v, float x, float vth) {
  v = v + (x - v) * 0.5f;
  float u = v - vth;
  float spike = (u >= 0.0f) ? 1.0f : 0.0f;
  v = (u >= 0.0f) ? 0.0f : v;
  return spike;
}

// BN + LIF + bit-pack; grid (NT_, B_, 3) over wide pbuf
__global__ __launch_bounds__(384) void bn_lif_pack_kernel(
    const float* __restrict__ pbuf, const float* __restrict__ bn,
    const float* __restrict__ g0, const float* __restrict__ g1, const float* __restrict__ g2,
    const float* __restrict__ be0, const float* __restrict__ be1, const float* __restrict__ be2,
    uint32_t* __restrict__ pack) {
  int c = threadIdx.x;
  int n = blockIdx.x, b = blockIdx.y, z = blockIdx.z;
  const float* g  = (z == 0) ? g0 : (z == 1) ? g1 : g2;
  const float* be = (z == 0) ? be0 : (z == 1) ? be1 : be2;
  int cg = z * C_ + c;
  float mean = bn[cg * 2 + 0], sd = bn[cg * 2 + 1];
  float gg = g[c], bb = be[c];
  int h = c >> 5;
  float v = 0.f;
  uint32_t* pko = pack + (size_t)z * (T_ * B_ * H_ * NT_);
  for (int t = 0; t < T_; ++t) {
    size_t row = (size_t)(t * B_ + b) * NT_ + n;
    float p = pbuf[row * NW_ + cg];
    float o = (gg * (p - mean)) / sd + bb;
    float spike = lif_step(v, o, 1.0f);
    unsigned long long m = __ballot(spike != 0.0f);
    if ((c & 31) == 0) {
      uint32_t pt = (c & 32) ? (uint32_t)(m >> 32) : (uint32_t)m;
      pko[((size_t)(t * B_ + b) * H_ + h) * NT_ + n] = pt;
    }
  }
}

// ---------------- attention: Z = k^T v per (t,b,h); grid 768 ----------------
__global__ __launch_bounds__(256) void zcalc_kernel(
    const uint32_t* __restrict__ kp, const uint32_t* __restrict__ vp,
    int* __restrict__ zbuf) {
  __shared__ uint32_t kT[32][8], vT[32][8];
  const int tbh = blockIdx.x;
  const int tid = threadIdx.x, lane = tid & 63, w = tid >> 6;
  size_t base = (size_t)tbh * NT_;
  uint32_t km = (tid < NT_) ? kp[base + tid] : 0u;
  uint32_t vm = (tid < NT_) ? vp[base + tid] : 0u;
#pragma unroll
  for (int j = 0; j < 32; ++j) {
    unsigned long long bk = __ballot((km >> j) & 1u);
    unsigned long long bv = __ballot((vm >> j) & 1u);
    if (lane == 0) {
      kT[j][2 * w] = (uint32_t)bk; kT[j][2 * w + 1] = (uint32_t)(bk >> 32);
      vT[j][2 * w] = (uint32_t)bv; vT[j][2 * w + 1] = (uint32_t)(bv >> 32);
    }
  }
  __syncthreads();
  int* Zg = zbuf + (size_t)tbh * 1024;
  for (int pz = tid; pz < 1024; pz += 256) {
    int j = pz >> 5, dd = pz & 31;
    int z = 0;
#pragma unroll
    for (int ww = 0; ww < 8; ++ww) z += __popc(kT[j][ww] & vT[dd][ww]);
    Zg[pz] = z;
  }
}

// y = q·Z·0.125, fused attn_lif (vth=0.5), writes 32*spike bf16; grid (B_*H_, 4 chunks)
__global__ __launch_bounds__(256) void attn_apply_kernel(
    const uint32_t* __restrict__ qp, const int* __restrict__ zbuf,
    short* __restrict__ yq) {
  __shared__ int Zs[32][32];
  const int bh = blockIdx.x, chunk = blockIdx.y;
  const int b = bh / H_, h = bh % H_;
  const int tid = threadIdx.x;
  const int d = tid & 31, nn = tid >> 5;   // 8 token lanes
  const short one32 = f2bf_bits(32.f);
  const short zer = f2bf_bits(0.f);
  float vst[7];
#pragma unroll
  for (int i = 0; i < 7; ++i) vst[i] = 0.f;
  for (int t = 0; t < T_; ++t) {
    int tbh = (t * B_ + b) * H_ + h;
    const int* Zp = zbuf + (size_t)tbh * 1024;
    for (int i = tid; i < 1024; i += 256) ((int*)Zs)[i] = Zp[i];
    __syncthreads();
    int zc[32];
#pragma unroll
    for (int j = 0; j < 32; ++j) zc[j] = Zs[j][d];
    size_t qbase = (size_t)tbh * NT_;
#pragma unroll
    for (int i = 0; i < 7; ++i) {
      int no = i * 8 + nn;
      if (no < 49) {
        int n = chunk * 49 + no;
        uint32_t qm = qp[qbase + n];
        int a = 0;
#pragma unroll
        for (int j = 0; j < 32; ++j) a += ((qm >> j) & 1u) ? zc[j] : 0;
        float y = 0.125f * (float)a;          // exact multiple of 1/8
        float v = vst[i];
        v = v + (y - v) * 0.5f;
        short outv;
        if (v - 0.5f >= 0.f) { v = 0.f; outv = one32; } else { outv = zer; }
        vst[i] = v;
        yq[((size_t)(t * B_ + b) * NT_ + n) * C_ + h * 32 + d] = outv;
      }
    }
    __syncthreads();
  }
}

// final BN + LIF -> d_out (f32 spikes)
__global__ __launch_bounds__(384) void bn_lif_out_kernel(
    const float* __restrict__ p2, const float* __restrict__ bn,
    const float* __restrict__ g, const float* __restrict__ beta,
    float* __restrict__ out) {
  int c = threadIdx.x, n = blockIdx.x, b = blockIdx.y;
  float mean = bn[c * 2 + 0], sd = bn[c * 2 + 1];
  float gg = g[c], bb = beta[c];
  float v = 0.f;
  for (int t = 0; t < T_; ++t) {
    size_t idx = ((size_t)(t * B_ + b) * NT_ + n) * C_ + c;
    float o = (gg * (p2[idx] - mean)) / sd + bb;
    out[idx] = lif_step(v, o, 1.0f);
  }
}

// ---------------- launcher ----------------
extern "C" void kernel_launch(void* const* d_in, const int* in_sizes, int n_in,
                              void* d_out, int out_size, void* d_ws, size_t ws_size,
                              hipStream_t stream) {
  (void)in_sizes; (void)n_in; (void)out_size; (void)ws_size;
  const float* x = (const float*)d_in[0];
  const float* W[4]  = {(const float*)d_in[1],  (const float*)d_in[5],
                        (const float*)d_in[9],  (const float*)d_in[13]};
  const float* bv[4] = {(const float*)d_in[2],  (const float*)d_in[6],
                        (const float*)d_in[10], (const float*)d_in[14]};
  const float* g[4]  = {(const float*)d_in[3],  (const float*)d_in[7],
                        (const float*)d_in[11], (const float*)d_in[15]};
  const float* be[4] = {(const float*)d_in[4],  (const float*)d_in[8],
                        (const float*)d_in[12], (const float*)d_in[16]};
  float* out = (float*)d_out;

  char* ws = (char*)d_ws;
  unsigned*  slots = (unsigned*)(ws + 0);            // 16 u32
  float*     SC    = (float*)(ws + 0x40);            // 8 f32
  float*     bnp   = (float*)(ws + 0x80);            // [1152][2] f32 (stage1)
  float*     bn2   = (float*)(ws + 0x6000);          // [384][2] f32
  float*     ccq   = (float*)(ws + 0x8000);          // [4][384] f32
  long long* part  = (long long*)(ws + 0x10000);     // [98][1152][2] i64 (1.77MB)
  long long* part2 = (long long*)(ws + 0x200000);    // [98][384][2] i64
  uint32_t*  pack  = (uint32_t*)(ws + 0x300000);     // [3][150528] u32
  int*       zbuf  = (int*)(ws + 0x500000);          // [768][1024] i32 (3MB)
  short*     wq    = (short*)(ws + 0x800000);        // [4][384][384] bf16
  short*     xq    = (short*)(ws + 0xA00000);        // [12544][384] bf16
  short*     yq    = (short*)(ws + 0x1400000);       // [12544][384] bf16
  float*     pwide = (float*)(ws + 0x1E00000);       // [12544][1152] f32 (57.8MB)
  float*     pbuf2 = (float*)(ws + 0x5600000);       // [12544][384] f32

  hipMemsetAsync(slots, 0, 64, stream);
  absmax_x_kernel<<<512, 256, 0, stream>>>(x, PBUF_ELEMS / 4, slots + 0);
  absmax_wb_kernel<<<dim3(64, 4), 256, 0, stream>>>(
      W[0], W[1], W[2], W[3], bv[0], bv[1], bv[2], bv[3], slots);
  scales_kernel<<<1, 64, 0, stream>>>(slots, SC);

  quant_x_kernel<<<4704, 256, 0, stream>>>(x, SC, xq);
  quant_w_kernel<<<dim3(576, 4), 256, 0, stream>>>(
      W[0], W[1], W[2], W[3], bv[0], bv[1], bv[2], bv[3], SC, wq, ccq);

  // stage 1: one wide GEMM (N=1152 = q|k|v), stats, BN+LIF+pack
  mfma_gemm_kernel<<<dim3(98, 9), 256, 0, stream>>>(
      xq, wq, ccq, SC, 0, 1, NW_, pwide, part);
  stats_final_kernel<<<3, 384, 0, stream>>>(part, SC, 1, NW_, bnp);
  bn_lif_pack_kernel<<<dim3(NT_, B_, 3), 384, 0, stream>>>(
      pwide, bnp, g[0], g[1], g[2], be[0], be[1], be[2], pack);

  // attention: Z per (t,b,h), then q·Z + attn_lif (writes 32*spike bf16)
  zcalc_kernel<<<T_ * B_ * H_, 256, 0, stream>>>(pack + 150528, pack + 2 * 150528, zbuf);
  attn_apply_kernel<<<dim3(B_ * H_, 4), 256, 0, stream>>>(pack, zbuf, yq);

  // stage 2: proj GEMM -> stats -> BN+LIF -> out
  mfma_gemm_kernel<<<dim3(98, 3), 256, 0, stream>>>(
      yq, wq + 3ull * C_ * C_, ccq + 3 * C_, SC, 5, 4, C_, pbuf2, part2);
  stats_final_kernel<<<1, 384, 0, stream>>>(part2, SC, 4, C_, bn2);
  bn_lif_out_kernel<<<dim3(NT_, B_), 384, 0, stream>>>(pbuf2, bn2, g[3], be[3], out);
}